// Round 12
// baseline (669.307 us; speedup 1.0000x reference)
//
#include <hip/hip_runtime.h>
#include <hip/hip_bf16.h>
#include <hip/hip_cooperative_groups.h>

namespace cg = cooperative_groups;

// Segment-sum via CSR build + atomic-free gather, fused into ONE cooperative
// kernel (6 phases split by grid.sync) to kill inter-kernel dispatch gaps and
// keep edge/rank L2-hot across phases. Internals = R8 (149.2us):
// R=8 blockIdx-replica rank-hist, LDS scans, plain place, R6 gather loop.
// R10's nt stores reverted (regressed +11us: perm CSR-slot writes DO merge
// in L2 under write-allocate; nt forced per-4B HBM traffic).
// Fallback 1: cooperative launch error -> R8 multi-kernel path.
// Fallback 2: workspace too small -> direct atomic scatter.

#define F_DIM 64

typedef __attribute__((ext_vector_type(4))) float f4v;
typedef __attribute__((ext_vector_type(4))) int   i4v;

// ==================== fused cooperative kernel ====================
template <int R>
__global__ __launch_bounds__(256, 4) void fused_kernel(
    const int* __restrict__ edge, const int* __restrict__ dim_p,
    const float* __restrict__ edge_w,
    int* __restrict__ counts8, int* __restrict__ offsets,
    int* __restrict__ perm, int* __restrict__ partials,
    int* __restrict__ rank,       // aliases d_out; dead after phase 4
    float* __restrict__ out, int E, int N, int NB)
{
    cg::grid_group grid = cg::this_grid();
    __shared__ int s[256];
    const int t = threadIdx.x;
    const int tid = blockIdx.x * blockDim.x + t;
    const int nthr = gridDim.x * blockDim.x;
    const int row = (*dim_p == 1) ? 0 : 1;
    const int* er = edge + (size_t)row * E;

    // ---- phase 0: zero counts ----
    for (int i = tid; i < R * N; i += nthr) counts8[i] = 0;
    grid.sync();

    // ---- phase 1: rank-histogram (vec4), r = blockIdx&7 (~XCD-local) ----
    {
        const int r = blockIdx.x & (R - 1);
        int* cb = counts8 + (size_t)r * N;
        const int rtag = r << 24;
        const int nvec = E >> 2;
        const i4v* er4 = reinterpret_cast<const i4v*>(er);
        i4v* rank4 = reinterpret_cast<i4v*>(rank);
        for (int v = tid; v < nvec; v += nthr) {
            const i4v ev = er4[v];
            i4v rk;
            rk.x = atomicAdd(&cb[ev.x], 1) | rtag;
            rk.y = atomicAdd(&cb[ev.y], 1) | rtag;
            rk.z = atomicAdd(&cb[ev.z], 1) | rtag;
            rk.w = atomicAdd(&cb[ev.w], 1) | rtag;
            rank4[v] = rk;
        }
        for (int e = (E & ~3) + tid; e < E; e += nthr)   // tail (E%4)
            rank[e] = atomicAdd(&cb[er[e]], 1) | rtag;
    }
    grid.sync();

    // ---- phase 2: scanA per 256-chunk: block-local scan + partials ----
    for (int chunk = blockIdx.x; chunk < NB; chunk += gridDim.x) {
        const int idx = chunk * 256 + t;
        int c[R];
        int tot = 0;
        if (idx < N) {
            #pragma unroll
            for (int r = 0; r < R; ++r) { c[r] = counts8[(size_t)r * N + idx]; tot += c[r]; }
        }
        s[t] = tot;
        __syncthreads();
        for (int d = 1; d < 256; d <<= 1) {
            const int x = (t >= d) ? s[t - d] : 0;
            __syncthreads();
            s[t] += x;
            __syncthreads();
        }
        if (idx < N) {
            offsets[idx] = s[t] - tot;
            int run = 0;
            #pragma unroll
            for (int r = 0; r < R; ++r) { counts8[(size_t)r * N + idx] = run; run += c[r]; }
        }
        if (t == 255) partials[chunk] = s[255];
        __syncthreads();
    }
    grid.sync();

    // ---- phase 3: scanBC: every participating block scans partials in LDS ----
    for (int chunk = blockIdx.x; chunk < NB; chunk += gridDim.x) {
        const int v = (t < NB) ? partials[t] : 0;
        s[t] = v;
        __syncthreads();
        for (int d = 1; d < 256; d <<= 1) {
            const int x = (t >= d) ? s[t - d] : 0;
            __syncthreads();
            s[t] += x;
            __syncthreads();
        }
        const int prefix = s[chunk] - ((chunk < NB) ? partials[chunk] : 0);
        const int idx = chunk * 256 + t;
        if (idx < N) offsets[idx] += prefix;
        __syncthreads();
    }
    if (tid == 0) offsets[N] = E;
    grid.sync();

    // ---- phase 4: place (plain stores; L2 write-merge wins) ----
    {
        const int nvec = E >> 2;
        const i4v* er4 = reinterpret_cast<const i4v*>(er);
        const i4v* rank4 = reinterpret_cast<const i4v*>(rank);
        for (int v = tid; v < nvec; v += nthr) {
            const i4v ev = er4[v];
            const i4v rk = rank4[v];
            const int e = v << 2;
            perm[offsets[ev.x] + counts8[(size_t)((rk.x >> 24) & (R - 1)) * N + ev.x]
                 + (rk.x & 0xFFFFFF)] = e + 0;
            perm[offsets[ev.y] + counts8[(size_t)((rk.y >> 24) & (R - 1)) * N + ev.y]
                 + (rk.y & 0xFFFFFF)] = e + 1;
            perm[offsets[ev.z] + counts8[(size_t)((rk.z >> 24) & (R - 1)) * N + ev.z]
                 + (rk.z & 0xFFFFFF)] = e + 2;
            perm[offsets[ev.w] + counts8[(size_t)((rk.w >> 24) & (R - 1)) * N + ev.w]
                 + (rk.w & 0xFFFFFF)] = e + 3;
        }
        for (int e = (E & ~3) + tid; e < E; e += nthr) {  // tail
            const int seg = er[e];
            const int rk = rank[e];
            perm[offsets[seg] + counts8[(size_t)((rk >> 24) & (R - 1)) * N + seg]
                 + (rk & 0xFFFFFF)] = e;
        }
    }
    grid.sync();

    // ---- phase 5: gather (R6 loop; rank/d_out now dead, out overwritten) ----
    {
        const int lane = t & 63;
        const int wv = t >> 6;               // 0..3
        const int grp = lane >> 3;
        const int sub = (lane & 7) << 3;
        for (int node = blockIdx.x * 4 + wv; node < N; node += gridDim.x * 4) {
            const int beg = offsets[node];
            const int end = offsets[node + 1];
            f4v a0 = 0.0f, a1 = 0.0f;
            int j = beg + grp;
            while (j < end) {
                const int j1 = j + 8, j2 = j + 16, j3 = j + 24;
                const int e0 = perm[j];
                const int e1 = (j1 < end) ? perm[j1] : e0;
                const int e2 = (j2 < end) ? perm[j2] : e0;
                const int e3 = (j3 < end) ? perm[j3] : e0;
                const f4v* p0 = reinterpret_cast<const f4v*>(edge_w + (size_t)e0 * F_DIM + sub);
                const f4v* p1 = reinterpret_cast<const f4v*>(edge_w + (size_t)e1 * F_DIM + sub);
                const f4v* p2 = reinterpret_cast<const f4v*>(edge_w + (size_t)e2 * F_DIM + sub);
                const f4v* p3 = reinterpret_cast<const f4v*>(edge_w + (size_t)e3 * F_DIM + sub);
                const f4v u0 = p0[0], u1 = p0[1];
                const f4v v0 = p1[0], v1 = p1[1];
                const f4v w0 = p2[0], w1 = p2[1];
                const f4v x0 = p3[0], x1 = p3[1];
                a0 += u0; a1 += u1;
                if (j1 < end) { a0 += v0; a1 += v1; }
                if (j2 < end) { a0 += w0; a1 += w1; }
                if (j3 < end) { a0 += x0; a1 += x1; }
                j += 32;
            }
            #pragma unroll
            for (int m = 8; m < 64; m <<= 1) {
                a0.x += __shfl_xor(a0.x, m); a0.y += __shfl_xor(a0.y, m);
                a0.z += __shfl_xor(a0.z, m); a0.w += __shfl_xor(a0.w, m);
                a1.x += __shfl_xor(a1.x, m); a1.y += __shfl_xor(a1.y, m);
                a1.z += __shfl_xor(a1.z, m); a1.w += __shfl_xor(a1.w, m);
            }
            if (grp == 0) {
                float* o = out + (size_t)node * F_DIM + sub;
                *reinterpret_cast<f4v*>(o)     = a0;
                *reinterpret_cast<f4v*>(o + 4) = a1;
            }
        }
    }
}

// ==================== R8 separate kernels (fallback path) ====================
__global__ void zero_kernel(int* __restrict__ p, int n) {
    const int i = blockIdx.x * blockDim.x + threadIdx.x;
    if (i < n) p[i] = 0;
}

template <int R>
__global__ void rank_hist_kernel(const int* __restrict__ edge,
                                 const int* __restrict__ dim_p,
                                 int* __restrict__ counts8,
                                 int* __restrict__ rank, int E, int N) {
    const int row = (*dim_p == 1) ? 0 : 1;
    const int* er = edge + (size_t)row * E;
    const int stride = gridDim.x * blockDim.x;
    const int r = blockIdx.x & (R - 1);
    int* cb = counts8 + (size_t)r * N;
    const int rtag = r << 24;
    if ((E & 3) == 0) {
        const int nvec = E >> 2;
        const i4v* er4 = reinterpret_cast<const i4v*>(er);
        i4v* rank4 = reinterpret_cast<i4v*>(rank);
        for (int v = blockIdx.x * blockDim.x + threadIdx.x; v < nvec; v += stride) {
            const i4v ev = er4[v];
            i4v rk;
            rk.x = atomicAdd(&cb[ev.x], 1) | rtag;
            rk.y = atomicAdd(&cb[ev.y], 1) | rtag;
            rk.z = atomicAdd(&cb[ev.z], 1) | rtag;
            rk.w = atomicAdd(&cb[ev.w], 1) | rtag;
            rank4[v] = rk;
        }
    } else {
        for (int e = blockIdx.x * blockDim.x + threadIdx.x; e < E; e += stride)
            rank[e] = atomicAdd(&cb[er[e]], 1) | rtag;
    }
}

template <int R>
__global__ void scanA_kernel(int* __restrict__ counts8,
                             int* __restrict__ offsets,
                             int* __restrict__ partials, int N) {
    __shared__ int s[256];
    const int t = threadIdx.x;
    const int idx = blockIdx.x * 256 + t;
    int c[R];
    int tot = 0;
    if (idx < N) {
        #pragma unroll
        for (int r = 0; r < R; ++r) { c[r] = counts8[(size_t)r * N + idx]; tot += c[r]; }
    }
    s[t] = tot;
    __syncthreads();
    for (int d = 1; d < 256; d <<= 1) {
        const int x = (t >= d) ? s[t - d] : 0;
        __syncthreads();
        s[t] += x;
        __syncthreads();
    }
    if (idx < N) {
        offsets[idx] = s[t] - tot;
        int run = 0;
        #pragma unroll
        for (int r = 0; r < R; ++r) { counts8[(size_t)r * N + idx] = run; run += c[r]; }
    }
    if (t == 255) partials[blockIdx.x] = s[255];
}

__global__ void scanBC_kernel(int* __restrict__ offsets,
                              const int* __restrict__ partials,
                              int N, int E, int NB) {
    __shared__ int s[256];
    const int t = threadIdx.x;
    const int v = (t < NB) ? partials[t] : 0;
    s[t] = v;
    __syncthreads();
    for (int d = 1; d < 256; d <<= 1) {
        const int x = (t >= d) ? s[t - d] : 0;
        __syncthreads();
        s[t] += x;
        __syncthreads();
    }
    const int prefix = s[blockIdx.x] - ((blockIdx.x < NB) ? partials[blockIdx.x] : 0);
    const int idx = blockIdx.x * 256 + t;
    if (idx < N) offsets[idx] += prefix;
    if (idx == 0) offsets[N] = E;
}

template <int R>
__global__ void place_kernel(const int* __restrict__ edge,
                             const int* __restrict__ dim_p,
                             const int* __restrict__ offsets,
                             const int* __restrict__ counts8,
                             const int* __restrict__ rank,
                             int* __restrict__ perm, int E, int N) {
    const int row = (*dim_p == 1) ? 0 : 1;
    const int* er = edge + (size_t)row * E;
    const int stride = gridDim.x * blockDim.x;
    if ((E & 3) == 0) {
        const int nvec = E >> 2;
        const i4v* er4 = reinterpret_cast<const i4v*>(er);
        const i4v* rank4 = reinterpret_cast<const i4v*>(rank);
        for (int v = blockIdx.x * blockDim.x + threadIdx.x; v < nvec; v += stride) {
            const i4v ev = er4[v];
            const i4v rk = rank4[v];
            const int e = v << 2;
            perm[offsets[ev.x] + counts8[(size_t)((rk.x >> 24) & (R - 1)) * N + ev.x]
                 + (rk.x & 0xFFFFFF)] = e + 0;
            perm[offsets[ev.y] + counts8[(size_t)((rk.y >> 24) & (R - 1)) * N + ev.y]
                 + (rk.y & 0xFFFFFF)] = e + 1;
            perm[offsets[ev.z] + counts8[(size_t)((rk.z >> 24) & (R - 1)) * N + ev.z]
                 + (rk.z & 0xFFFFFF)] = e + 2;
            perm[offsets[ev.w] + counts8[(size_t)((rk.w >> 24) & (R - 1)) * N + ev.w]
                 + (rk.w & 0xFFFFFF)] = e + 3;
        }
    } else {
        for (int e = blockIdx.x * blockDim.x + threadIdx.x; e < E; e += stride) {
            const int seg = er[e];
            const int rk = rank[e];
            perm[offsets[seg] + counts8[(size_t)((rk >> 24) & (R - 1)) * N + seg]
                 + (rk & 0xFFFFFF)] = e;
        }
    }
}

__global__ __launch_bounds__(256) void gather_kernel(
    const float* __restrict__ edge_w,
    const int* __restrict__ offsets,
    const int* __restrict__ perm,
    float* __restrict__ out, int N) {
    const int node = blockIdx.x * 4 + (threadIdx.x >> 6);
    const int lane = threadIdx.x & 63;
    if (node >= N) return;
    const int beg = offsets[node];
    const int end = offsets[node + 1];
    const int grp = lane >> 3;
    const int sub = (lane & 7) << 3;
    f4v a0 = 0.0f, a1 = 0.0f;
    int j = beg + grp;
    while (j < end) {
        const int j1 = j + 8, j2 = j + 16, j3 = j + 24;
        const int e0 = perm[j];
        const int e1 = (j1 < end) ? perm[j1] : e0;
        const int e2 = (j2 < end) ? perm[j2] : e0;
        const int e3 = (j3 < end) ? perm[j3] : e0;
        const f4v* p0 = reinterpret_cast<const f4v*>(edge_w + (size_t)e0 * F_DIM + sub);
        const f4v* p1 = reinterpret_cast<const f4v*>(edge_w + (size_t)e1 * F_DIM + sub);
        const f4v* p2 = reinterpret_cast<const f4v*>(edge_w + (size_t)e2 * F_DIM + sub);
        const f4v* p3 = reinterpret_cast<const f4v*>(edge_w + (size_t)e3 * F_DIM + sub);
        const f4v u0 = p0[0], u1 = p0[1];
        const f4v v0 = p1[0], v1 = p1[1];
        const f4v w0 = p2[0], w1 = p2[1];
        const f4v x0 = p3[0], x1 = p3[1];
        a0 += u0; a1 += u1;
        if (j1 < end) { a0 += v0; a1 += v1; }
        if (j2 < end) { a0 += w0; a1 += w1; }
        if (j3 < end) { a0 += x0; a1 += x1; }
        j += 32;
    }
    #pragma unroll
    for (int m = 8; m < 64; m <<= 1) {
        a0.x += __shfl_xor(a0.x, m); a0.y += __shfl_xor(a0.y, m);
        a0.z += __shfl_xor(a0.z, m); a0.w += __shfl_xor(a0.w, m);
        a1.x += __shfl_xor(a1.x, m); a1.y += __shfl_xor(a1.y, m);
        a1.z += __shfl_xor(a1.z, m); a1.w += __shfl_xor(a1.w, m);
    }
    if (grp == 0) {
        float* o = out + (size_t)node * F_DIM + sub;
        *reinterpret_cast<f4v*>(o)     = a0;
        *reinterpret_cast<f4v*>(o + 4) = a1;
    }
}

__global__ void atomic_kernel(const int* __restrict__ edge,
                              const float* __restrict__ edge_w,
                              const int* __restrict__ dim_p,
                              float* __restrict__ out, int E) {
    const int row = (*dim_p == 1) ? 0 : 1;
    const long long total = (long long)E * 16;
    const long long stride = (long long)gridDim.x * blockDim.x;
    for (long long i = (long long)blockIdx.x * blockDim.x + threadIdx.x;
         i < total; i += stride) {
        const int e = (int)(i >> 4);
        const int c = ((int)i & 15) << 2;
        const int seg = edge[(long long)row * E + e];
        const float4 v = *reinterpret_cast<const float4*>(
            edge_w + (long long)e * F_DIM + c);
        float* o = out + (long long)seg * F_DIM + c;
        atomicAdd(o + 0, v.x);
        atomicAdd(o + 1, v.y);
        atomicAdd(o + 2, v.z);
        atomicAdd(o + 3, v.w);
    }
}

extern "C" void kernel_launch(void* const* d_in, const int* in_sizes, int n_in,
                              void* d_out, int out_size, void* d_ws, size_t ws_size,
                              hipStream_t stream) {
    const int*   edge   = (const int*)d_in[0];
    const float* edge_w = (const float*)d_in[1];
    const int*   dim_p  = (const int*)d_in[5];
    float*       out    = (float*)d_out;

    const int E = in_sizes[0] / 2;
    const int F = in_sizes[1] / E;           // 64
    const int N = out_size / F;              // 50000
    const int NB = (N + 255) / 256;          // 196

    const size_t need8 = ((size_t)8 * N + N + 1 + (size_t)E + 256) * sizeof(int);
    const size_t need1 = ((size_t)1 * N + N + 1 + (size_t)E + 256) * sizeof(int);
    const bool rank_fits = (size_t)E <= (size_t)out_size;
    if (ws_size < need1 || NB > 256 || !rank_fits) {
        (void)hipMemsetAsync(d_out, 0, (size_t)out_size * sizeof(float), stream);
        atomic_kernel<<<2048, 256, 0, stream>>>(edge, edge_w, dim_p, out, E);
        return;
    }
    const int R = (ws_size >= need8) ? 8 : 1;

    int* counts8  = (int*)d_ws;
    int* offsets  = counts8 + (size_t)R * N;
    int* perm     = offsets + N + 1;
    int* partials = perm + E;
    int* rank     = (int*)d_out;

    const int block = 256;

    if (R == 8) {
        // ---- fused cooperative path ----
        int E_ = E, N_ = N, NB_ = NB;
        void* args[] = { (void*)&edge, (void*)&dim_p, (void*)&edge_w,
                         (void*)&counts8, (void*)&offsets, (void*)&perm,
                         (void*)&partials, (void*)&rank, (void*)&out,
                         (void*)&E_, (void*)&N_, (void*)&NB_ };
        hipError_t err = hipLaunchCooperativeKernel(
            (const void*)fused_kernel<8>, dim3(1024), dim3(block), args, 0, stream);
        if (err == hipSuccess) return;
        // else fall through to multi-kernel path
    }

    const int gridV = min(4096, (E / 4 + block - 1) / block);
    const int gridE = min(4096, (E + block - 1) / block);
    const int gridZ = (R * N + block - 1) / block;

    zero_kernel<<<gridZ, block, 0, stream>>>(counts8, R * N);
    if (R == 8) {
        rank_hist_kernel<8><<<(E & 3) ? gridE : gridV, block, 0, stream>>>(
            edge, dim_p, counts8, rank, E, N);
        scanA_kernel<8><<<NB, block, 0, stream>>>(counts8, offsets, partials, N);
        scanBC_kernel<<<NB, block, 0, stream>>>(offsets, partials, N, E, NB);
        place_kernel<8><<<(E & 3) ? gridE : gridV, block, 0, stream>>>(
            edge, dim_p, offsets, counts8, rank, perm, E, N);
    } else {
        rank_hist_kernel<1><<<(E & 3) ? gridE : gridV, block, 0, stream>>>(
            edge, dim_p, counts8, rank, E, N);
        scanA_kernel<1><<<NB, block, 0, stream>>>(counts8, offsets, partials, N);
        scanBC_kernel<<<NB, block, 0, stream>>>(offsets, partials, N, E, NB);
        place_kernel<1><<<(E & 3) ? gridE : gridV, block, 0, stream>>>(
            edge, dim_p, offsets, counts8, rank, perm, E, N);
    }
    const int gridN = (N + 3) / 4;
    gather_kernel<<<gridN, block, 0, stream>>>(edge_w, offsets, perm, out, N);
}

// Round 13
// 274.927 us; speedup vs baseline: 2.4345x; 2.4345x over previous
//
#include <hip/hip_runtime.h>
#include <hip/hip_bf16.h>

// Segment-sum via CSR build + atomic-free gather.
// R13 = MEASUREMENT ROUND: exact R8 pipeline (best known, 149.2us), but
// gather_kernel launched 3x (it is idempotent: fully overwrites out from
// unchanged offsets/perm). (dur - 149.2)/2 = exact gather cost inside the
// timed graph. R12's cooperative fusion reverted (669us: 1024-block cap
// strangled gather MLP; 253GB/s, VALUBusy 1.4%).

#define F_DIM 64

typedef __attribute__((ext_vector_type(4))) float f4v;
typedef __attribute__((ext_vector_type(4))) int   i4v;

// ---------- zero counts ----------
__global__ void zero_kernel(int* __restrict__ p, int n) {
    const int i = blockIdx.x * blockDim.x + threadIdx.x;
    if (i < n) p[i] = 0;
}

// ---------- rank-histogram: counts8[r*N+seg]++, rank[e] = old | r<<24 ----------
template <int R>
__global__ void rank_hist_kernel(const int* __restrict__ edge,
                                 const int* __restrict__ dim_p,
                                 int* __restrict__ counts8,
                                 int* __restrict__ rank, int E, int N) {
    const int row = (*dim_p == 1) ? 0 : 1;
    const int* er = edge + (size_t)row * E;
    const int stride = gridDim.x * blockDim.x;
    const int r = blockIdx.x & (R - 1);          // ~XCD-local replica
    int* cb = counts8 + (size_t)r * N;
    const int rtag = r << 24;
    if ((E & 3) == 0) {
        const int nvec = E >> 2;
        const i4v* er4 = reinterpret_cast<const i4v*>(er);
        i4v* rank4 = reinterpret_cast<i4v*>(rank);
        for (int v = blockIdx.x * blockDim.x + threadIdx.x; v < nvec; v += stride) {
            const i4v ev = er4[v];
            i4v rk;
            rk.x = atomicAdd(&cb[ev.x], 1) | rtag;
            rk.y = atomicAdd(&cb[ev.y], 1) | rtag;
            rk.z = atomicAdd(&cb[ev.z], 1) | rtag;
            rk.w = atomicAdd(&cb[ev.w], 1) | rtag;
            rank4[v] = rk;
        }
    } else {
        for (int e = blockIdx.x * blockDim.x + threadIdx.x; e < E; e += stride)
            rank[e] = atomicAdd(&cb[er[e]], 1) | rtag;
    }
}

// ---------- scan A: fold replicas, per-block scan, replica prefixes ----------
template <int R>
__global__ void scanA_kernel(int* __restrict__ counts8,
                             int* __restrict__ offsets,
                             int* __restrict__ partials, int N) {
    __shared__ int s[256];
    const int t = threadIdx.x;
    const int idx = blockIdx.x * 256 + t;
    int c[R];
    int tot = 0;
    if (idx < N) {
        #pragma unroll
        for (int r = 0; r < R; ++r) { c[r] = counts8[(size_t)r * N + idx]; tot += c[r]; }
    }
    s[t] = tot;
    __syncthreads();
    for (int d = 1; d < 256; d <<= 1) {
        const int x = (t >= d) ? s[t - d] : 0;
        __syncthreads();
        s[t] += x;
        __syncthreads();
    }
    if (idx < N) {
        offsets[idx] = s[t] - tot;              // block-local exclusive
        int run = 0;
        #pragma unroll
        for (int r = 0; r < R; ++r) {           // per-replica exclusive prefix
            counts8[(size_t)r * N + idx] = run;
            run += c[r];
        }
    }
    if (t == 255) partials[blockIdx.x] = s[255];
}

// ---------- scan BC: each block scans all partials in LDS, applies ----------
__global__ void scanBC_kernel(int* __restrict__ offsets,
                              const int* __restrict__ partials,
                              int N, int E, int NB) {
    __shared__ int s[256];
    const int t = threadIdx.x;
    const int v = (t < NB) ? partials[t] : 0;
    s[t] = v;
    __syncthreads();
    for (int d = 1; d < 256; d <<= 1) {
        const int x = (t >= d) ? s[t - d] : 0;
        __syncthreads();
        s[t] += x;
        __syncthreads();
    }
    const int prefix = s[blockIdx.x] - ((blockIdx.x < NB) ? partials[blockIdx.x] : 0);
    const int idx = blockIdx.x * 256 + t;
    if (idx < N) offsets[idx] += prefix;
    if (idx == 0) offsets[N] = E;
}

// ---------- place: perm[offsets[seg]+replicaPrefix+rank] = e ----------
template <int R>
__global__ void place_kernel(const int* __restrict__ edge,
                             const int* __restrict__ dim_p,
                             const int* __restrict__ offsets,
                             const int* __restrict__ counts8,  // replica prefixes
                             const int* __restrict__ rank,
                             int* __restrict__ perm, int E, int N) {
    const int row = (*dim_p == 1) ? 0 : 1;
    const int* er = edge + (size_t)row * E;
    const int stride = gridDim.x * blockDim.x;
    if ((E & 3) == 0) {
        const int nvec = E >> 2;
        const i4v* er4 = reinterpret_cast<const i4v*>(er);
        const i4v* rank4 = reinterpret_cast<const i4v*>(rank);
        for (int v = blockIdx.x * blockDim.x + threadIdx.x; v < nvec; v += stride) {
            const i4v ev = er4[v];
            const i4v rk = rank4[v];
            const int e = v << 2;
            perm[offsets[ev.x] + counts8[(size_t)((rk.x >> 24) & (R - 1)) * N + ev.x]
                 + (rk.x & 0xFFFFFF)] = e + 0;
            perm[offsets[ev.y] + counts8[(size_t)((rk.y >> 24) & (R - 1)) * N + ev.y]
                 + (rk.y & 0xFFFFFF)] = e + 1;
            perm[offsets[ev.z] + counts8[(size_t)((rk.z >> 24) & (R - 1)) * N + ev.z]
                 + (rk.z & 0xFFFFFF)] = e + 2;
            perm[offsets[ev.w] + counts8[(size_t)((rk.w >> 24) & (R - 1)) * N + ev.w]
                 + (rk.w & 0xFFFFFF)] = e + 3;
        }
    } else {
        for (int e = blockIdx.x * blockDim.x + threadIdx.x; e < E; e += stride) {
            const int seg = er[e];
            const int rk = rank[e];
            perm[offsets[seg] + counts8[(size_t)((rk >> 24) & (R - 1)) * N + seg]
                 + (rk & 0xFFFFFF)] = e;
        }
    }
}

// ---------- gather-reduce: one wave per node (R6 loop) ----------
__global__ __launch_bounds__(256) void gather_kernel(
    const float* __restrict__ edge_w,
    const int* __restrict__ offsets,
    const int* __restrict__ perm,
    float* __restrict__ out, int N) {
    const int node = blockIdx.x * 4 + (threadIdx.x >> 6);
    const int lane = threadIdx.x & 63;
    if (node >= N) return;
    const int beg = offsets[node];
    const int end = offsets[node + 1];
    const int grp = lane >> 3;
    const int sub = (lane & 7) << 3;
    f4v a0 = 0.0f, a1 = 0.0f;
    int j = beg + grp;
    while (j < end) {
        const int j1 = j + 8, j2 = j + 16, j3 = j + 24;
        const int e0 = perm[j];
        const int e1 = (j1 < end) ? perm[j1] : e0;
        const int e2 = (j2 < end) ? perm[j2] : e0;
        const int e3 = (j3 < end) ? perm[j3] : e0;
        const f4v* p0 = reinterpret_cast<const f4v*>(edge_w + (size_t)e0 * F_DIM + sub);
        const f4v* p1 = reinterpret_cast<const f4v*>(edge_w + (size_t)e1 * F_DIM + sub);
        const f4v* p2 = reinterpret_cast<const f4v*>(edge_w + (size_t)e2 * F_DIM + sub);
        const f4v* p3 = reinterpret_cast<const f4v*>(edge_w + (size_t)e3 * F_DIM + sub);
        const f4v u0 = p0[0], u1 = p0[1];
        const f4v v0 = p1[0], v1 = p1[1];
        const f4v w0 = p2[0], w1 = p2[1];
        const f4v x0 = p3[0], x1 = p3[1];
        a0 += u0; a1 += u1;
        if (j1 < end) { a0 += v0; a1 += v1; }
        if (j2 < end) { a0 += w0; a1 += w1; }
        if (j3 < end) { a0 += x0; a1 += x1; }
        j += 32;
    }
    #pragma unroll
    for (int m = 8; m < 64; m <<= 1) {
        a0.x += __shfl_xor(a0.x, m); a0.y += __shfl_xor(a0.y, m);
        a0.z += __shfl_xor(a0.z, m); a0.w += __shfl_xor(a0.w, m);
        a1.x += __shfl_xor(a1.x, m); a1.y += __shfl_xor(a1.y, m);
        a1.z += __shfl_xor(a1.z, m); a1.w += __shfl_xor(a1.w, m);
    }
    if (grp == 0) {
        float* o = out + (size_t)node * F_DIM + sub;
        *reinterpret_cast<f4v*>(o)     = a0;
        *reinterpret_cast<f4v*>(o + 4) = a1;
    }
}

// ---------- fallback: direct atomic scatter ----------
__global__ void atomic_kernel(const int* __restrict__ edge,
                              const float* __restrict__ edge_w,
                              const int* __restrict__ dim_p,
                              float* __restrict__ out, int E) {
    const int row = (*dim_p == 1) ? 0 : 1;
    const long long total = (long long)E * 16;
    const long long stride = (long long)gridDim.x * blockDim.x;
    for (long long i = (long long)blockIdx.x * blockDim.x + threadIdx.x;
         i < total; i += stride) {
        const int e = (int)(i >> 4);
        const int c = ((int)i & 15) << 2;
        const int seg = edge[(long long)row * E + e];
        const float4 v = *reinterpret_cast<const float4*>(
            edge_w + (long long)e * F_DIM + c);
        float* o = out + (long long)seg * F_DIM + c;
        atomicAdd(o + 0, v.x);
        atomicAdd(o + 1, v.y);
        atomicAdd(o + 2, v.z);
        atomicAdd(o + 3, v.w);
    }
}

extern "C" void kernel_launch(void* const* d_in, const int* in_sizes, int n_in,
                              void* d_out, int out_size, void* d_ws, size_t ws_size,
                              hipStream_t stream) {
    const int*   edge   = (const int*)d_in[0];
    const float* edge_w = (const float*)d_in[1];
    const int*   dim_p  = (const int*)d_in[5];
    float*       out    = (float*)d_out;

    const int E = in_sizes[0] / 2;
    const int F = in_sizes[1] / E;           // 64
    const int N = out_size / F;              // 50000
    const int NB = (N + 255) / 256;          // 196

    const size_t need8 = ((size_t)8 * N + N + 1 + (size_t)E + 256) * sizeof(int);
    const size_t need1 = ((size_t)1 * N + N + 1 + (size_t)E + 256) * sizeof(int);
    const bool rank_fits = (size_t)E <= (size_t)out_size;
    if (ws_size < need1 || NB > 256 || !rank_fits) {
        (void)hipMemsetAsync(d_out, 0, (size_t)out_size * sizeof(float), stream);
        atomic_kernel<<<2048, 256, 0, stream>>>(edge, edge_w, dim_p, out, E);
        return;
    }
    const int R = (ws_size >= need8) ? 8 : 1;

    int* counts8  = (int*)d_ws;
    int* offsets  = counts8 + (size_t)R * N;
    int* perm     = offsets + N + 1;
    int* partials = perm + E;
    int* rank     = (int*)d_out;             // scratch; overwritten by gather

    const int block = 256;
    const int gridV = min(4096, (E / 4 + block - 1) / block);
    const int gridE = min(4096, (E + block - 1) / block);
    const int gridZ = (R * N + block - 1) / block;

    zero_kernel<<<gridZ, block, 0, stream>>>(counts8, R * N);
    if (R == 8) {
        rank_hist_kernel<8><<<(E & 3) ? gridE : gridV, block, 0, stream>>>(
            edge, dim_p, counts8, rank, E, N);
        scanA_kernel<8><<<NB, block, 0, stream>>>(counts8, offsets, partials, N);
        scanBC_kernel<<<NB, block, 0, stream>>>(offsets, partials, N, E, NB);
        place_kernel<8><<<(E & 3) ? gridE : gridV, block, 0, stream>>>(
            edge, dim_p, offsets, counts8, rank, perm, E, N);
    } else {
        rank_hist_kernel<1><<<(E & 3) ? gridE : gridV, block, 0, stream>>>(
            edge, dim_p, counts8, rank, E, N);
        scanA_kernel<1><<<NB, block, 0, stream>>>(counts8, offsets, partials, N);
        scanBC_kernel<<<NB, block, 0, stream>>>(offsets, partials, N, E, NB);
        place_kernel<1><<<(E & 3) ? gridE : gridV, block, 0, stream>>>(
            edge, dim_p, offsets, counts8, rank, perm, E, N);
    }

    const int gridN = (N + 3) / 4;
    // MEASUREMENT: gather is idempotent; 3 launches -> (dur - base)/2 = gather cost.
    gather_kernel<<<gridN, block, 0, stream>>>(edge_w, offsets, perm, out, N);
    gather_kernel<<<gridN, block, 0, stream>>>(edge_w, offsets, perm, out, N);
    gather_kernel<<<gridN, block, 0, stream>>>(edge_w, offsets, perm, out, N);
}

// Round 14
// 150.863 us; speedup vs baseline: 4.4365x; 1.8224x over previous
//
#include <hip/hip_runtime.h>
#include <hip/hip_bf16.h>

// Segment-sum via CSR build + atomic-free gather.
// out[seg, f] = sum over edges e with edge[row][e]==seg of edge_w[e, f].
// row = 0 if dim==1 else 1 (read on device).
//
// R14: drop scanBC entirely (5 kernels, was 6). scanA writes block-local
// exclusive offsets + per-256-chunk partials; place and gather each
// reconstruct the global offset with a 196-int LDS scan per block (~40
// instr, amortized). Saves 1 launch gap + 400KB offsets rw + scanBC.
// Measured split (R13): gather 62.9us (~86% of copy-BW ceiling),
// build+gaps 86.3us. Everything else byte-identical to R8 (149.2us best).

#define F_DIM 64

typedef __attribute__((ext_vector_type(4))) float f4v;
typedef __attribute__((ext_vector_type(4))) int   i4v;

// ---------- zero counts (vec4) ----------
__global__ void zero_kernel(int* __restrict__ p, int n) {
    const int i = blockIdx.x * blockDim.x + threadIdx.x;
    const int nv = n >> 2;
    if (i < nv) reinterpret_cast<i4v*>(p)[i] = (i4v)0;
    const int tail = (nv << 2) + i;
    if (tail < n && i < 4) p[tail] = 0;   // up to 3 tail ints
}

// ---------- rank-histogram: counts8[r*N+seg]++, rank[e] = old | r<<24 ----------
template <int R>
__global__ void rank_hist_kernel(const int* __restrict__ edge,
                                 const int* __restrict__ dim_p,
                                 int* __restrict__ counts8,
                                 int* __restrict__ rank, int E, int N) {
    const int row = (*dim_p == 1) ? 0 : 1;
    const int* er = edge + (size_t)row * E;
    const int stride = gridDim.x * blockDim.x;
    const int r = blockIdx.x & (R - 1);          // ~XCD-local replica
    int* cb = counts8 + (size_t)r * N;
    const int rtag = r << 24;
    if ((E & 3) == 0) {
        const int nvec = E >> 2;
        const i4v* er4 = reinterpret_cast<const i4v*>(er);
        i4v* rank4 = reinterpret_cast<i4v*>(rank);
        for (int v = blockIdx.x * blockDim.x + threadIdx.x; v < nvec; v += stride) {
            const i4v ev = er4[v];
            i4v rk;
            rk.x = atomicAdd(&cb[ev.x], 1) | rtag;
            rk.y = atomicAdd(&cb[ev.y], 1) | rtag;
            rk.z = atomicAdd(&cb[ev.z], 1) | rtag;
            rk.w = atomicAdd(&cb[ev.w], 1) | rtag;
            rank4[v] = rk;
        }
    } else {
        for (int e = blockIdx.x * blockDim.x + threadIdx.x; e < E; e += stride)
            rank[e] = atomicAdd(&cb[er[e]], 1) | rtag;
    }
}

// ---------- scan A: fold replicas, block-local scan, replica prefixes ----------
template <int R>
__global__ void scanA_kernel(int* __restrict__ counts8,
                             int* __restrict__ offsets,
                             int* __restrict__ partials, int N) {
    __shared__ int s[256];
    const int t = threadIdx.x;
    const int idx = blockIdx.x * 256 + t;
    int c[R];
    int tot = 0;
    if (idx < N) {
        #pragma unroll
        for (int r = 0; r < R; ++r) { c[r] = counts8[(size_t)r * N + idx]; tot += c[r]; }
    }
    s[t] = tot;
    __syncthreads();
    for (int d = 1; d < 256; d <<= 1) {
        const int x = (t >= d) ? s[t - d] : 0;
        __syncthreads();
        s[t] += x;
        __syncthreads();
    }
    if (idx < N) {
        offsets[idx] = s[t] - tot;              // block-local exclusive
        int run = 0;
        #pragma unroll
        for (int r = 0; r < R; ++r) {           // per-replica exclusive prefix
            counts8[(size_t)r * N + idx] = run;
            run += c[r];
        }
    }
    if (t == 255) partials[blockIdx.x] = s[255];
}

// ---------- shared helper: LDS exclusive-prefix of partials ----------
// After return, s[c] = sum of partials[0..c-1] for c < 256.
__device__ __forceinline__ void lds_partials_prefix(
    int* s, const int* __restrict__ partials, int NB, int t) {
    const int v = (t < NB) ? partials[t] : 0;
    s[t] = v;
    __syncthreads();
    for (int d = 1; d < 256; d <<= 1) {
        const int x = (t >= d) ? s[t - d] : 0;
        __syncthreads();
        s[t] += x;
        __syncthreads();
    }
    const int pre = s[t] - v;                  // exclusive
    __syncthreads();
    s[t] = pre;
    __syncthreads();
}

// ---------- place: perm[goff(seg)+replicaPrefix+rank] = e ----------
template <int R>
__global__ void place_kernel(const int* __restrict__ edge,
                             const int* __restrict__ dim_p,
                             const int* __restrict__ offsets,   // block-local
                             const int* __restrict__ counts8,   // replica prefixes
                             const int* __restrict__ rank,
                             const int* __restrict__ partials,
                             int* __restrict__ perm, int E, int N, int NB) {
    __shared__ int s[256];
    lds_partials_prefix(s, partials, NB, threadIdx.x);
    const int row = (*dim_p == 1) ? 0 : 1;
    const int* er = edge + (size_t)row * E;
    const int stride = gridDim.x * blockDim.x;
    if ((E & 3) == 0) {
        const int nvec = E >> 2;
        const i4v* er4 = reinterpret_cast<const i4v*>(er);
        const i4v* rank4 = reinterpret_cast<const i4v*>(rank);
        for (int v = blockIdx.x * blockDim.x + threadIdx.x; v < nvec; v += stride) {
            const i4v ev = er4[v];
            const i4v rk = rank4[v];
            const int e = v << 2;
            perm[s[ev.x >> 8] + offsets[ev.x]
                 + counts8[(size_t)((rk.x >> 24) & (R - 1)) * N + ev.x]
                 + (rk.x & 0xFFFFFF)] = e + 0;
            perm[s[ev.y >> 8] + offsets[ev.y]
                 + counts8[(size_t)((rk.y >> 24) & (R - 1)) * N + ev.y]
                 + (rk.y & 0xFFFFFF)] = e + 1;
            perm[s[ev.z >> 8] + offsets[ev.z]
                 + counts8[(size_t)((rk.z >> 24) & (R - 1)) * N + ev.z]
                 + (rk.z & 0xFFFFFF)] = e + 2;
            perm[s[ev.w >> 8] + offsets[ev.w]
                 + counts8[(size_t)((rk.w >> 24) & (R - 1)) * N + ev.w]
                 + (rk.w & 0xFFFFFF)] = e + 3;
        }
    } else {
        for (int e = blockIdx.x * blockDim.x + threadIdx.x; e < E; e += stride) {
            const int seg = er[e];
            const int rk = rank[e];
            perm[s[seg >> 8] + offsets[seg]
                 + counts8[(size_t)((rk >> 24) & (R - 1)) * N + seg]
                 + (rk & 0xFFFFFF)] = e;
        }
    }
}

// ---------- gather-reduce: one wave per node (R6 loop, local offsets) ----------
__global__ __launch_bounds__(256) void gather_kernel(
    const float* __restrict__ edge_w,
    const int* __restrict__ offsets,   // block-local
    const int* __restrict__ partials,
    const int* __restrict__ perm,
    float* __restrict__ out, int N, int E, int NB) {
    __shared__ int s[256];
    lds_partials_prefix(s, partials, NB, threadIdx.x);
    const int node = blockIdx.x * 4 + (threadIdx.x >> 6);
    const int lane = threadIdx.x & 63;
    if (node >= N) return;
    const int beg = s[node >> 8] + offsets[node];
    const int end = (node + 1 == N) ? E : s[(node + 1) >> 8] + offsets[node + 1];
    const int grp = lane >> 3;
    const int sub = (lane & 7) << 3;
    f4v a0 = 0.0f, a1 = 0.0f;
    int j = beg + grp;
    while (j < end) {
        const int j1 = j + 8, j2 = j + 16, j3 = j + 24;
        const int e0 = perm[j];
        const int e1 = (j1 < end) ? perm[j1] : e0;
        const int e2 = (j2 < end) ? perm[j2] : e0;
        const int e3 = (j3 < end) ? perm[j3] : e0;
        const f4v* p0 = reinterpret_cast<const f4v*>(edge_w + (size_t)e0 * F_DIM + sub);
        const f4v* p1 = reinterpret_cast<const f4v*>(edge_w + (size_t)e1 * F_DIM + sub);
        const f4v* p2 = reinterpret_cast<const f4v*>(edge_w + (size_t)e2 * F_DIM + sub);
        const f4v* p3 = reinterpret_cast<const f4v*>(edge_w + (size_t)e3 * F_DIM + sub);
        const f4v u0 = p0[0], u1 = p0[1];
        const f4v v0 = p1[0], v1 = p1[1];
        const f4v w0 = p2[0], w1 = p2[1];
        const f4v x0 = p3[0], x1 = p3[1];
        a0 += u0; a1 += u1;
        if (j1 < end) { a0 += v0; a1 += v1; }
        if (j2 < end) { a0 += w0; a1 += w1; }
        if (j3 < end) { a0 += x0; a1 += x1; }
        j += 32;
    }
    #pragma unroll
    for (int m = 8; m < 64; m <<= 1) {
        a0.x += __shfl_xor(a0.x, m); a0.y += __shfl_xor(a0.y, m);
        a0.z += __shfl_xor(a0.z, m); a0.w += __shfl_xor(a0.w, m);
        a1.x += __shfl_xor(a1.x, m); a1.y += __shfl_xor(a1.y, m);
        a1.z += __shfl_xor(a1.z, m); a1.w += __shfl_xor(a1.w, m);
    }
    if (grp == 0) {
        float* o = out + (size_t)node * F_DIM + sub;
        *reinterpret_cast<f4v*>(o)     = a0;
        *reinterpret_cast<f4v*>(o + 4) = a1;
    }
}

// ---------- fallback: direct atomic scatter ----------
__global__ void atomic_kernel(const int* __restrict__ edge,
                              const float* __restrict__ edge_w,
                              const int* __restrict__ dim_p,
                              float* __restrict__ out, int E) {
    const int row = (*dim_p == 1) ? 0 : 1;
    const long long total = (long long)E * 16;
    const long long stride = (long long)gridDim.x * blockDim.x;
    for (long long i = (long long)blockIdx.x * blockDim.x + threadIdx.x;
         i < total; i += stride) {
        const int e = (int)(i >> 4);
        const int c = ((int)i & 15) << 2;
        const int seg = edge[(long long)row * E + e];
        const float4 v = *reinterpret_cast<const float4*>(
            edge_w + (long long)e * F_DIM + c);
        float* o = out + (long long)seg * F_DIM + c;
        atomicAdd(o + 0, v.x);
        atomicAdd(o + 1, v.y);
        atomicAdd(o + 2, v.z);
        atomicAdd(o + 3, v.w);
    }
}

extern "C" void kernel_launch(void* const* d_in, const int* in_sizes, int n_in,
                              void* d_out, int out_size, void* d_ws, size_t ws_size,
                              hipStream_t stream) {
    const int*   edge   = (const int*)d_in[0];
    const float* edge_w = (const float*)d_in[1];
    const int*   dim_p  = (const int*)d_in[5];
    float*       out    = (float*)d_out;

    const int E = in_sizes[0] / 2;
    const int F = in_sizes[1] / E;           // 64
    const int N = out_size / F;              // 50000
    const int NB = (N + 255) / 256;          // 196

    const size_t need8 = ((size_t)8 * N + N + 1 + (size_t)E + 256) * sizeof(int);
    const size_t need1 = ((size_t)1 * N + N + 1 + (size_t)E + 256) * sizeof(int);
    const bool rank_fits = (size_t)E <= (size_t)out_size;
    if (ws_size < need1 || NB > 256 || !rank_fits) {
        (void)hipMemsetAsync(d_out, 0, (size_t)out_size * sizeof(float), stream);
        atomic_kernel<<<2048, 256, 0, stream>>>(edge, edge_w, dim_p, out, E);
        return;
    }
    const int R = (ws_size >= need8) ? 8 : 1;

    int* counts8  = (int*)d_ws;
    int* offsets  = counts8 + (size_t)R * N;   // block-local exclusive offsets
    int* perm     = offsets + N + 1;
    int* partials = perm + E;
    int* rank     = (int*)d_out;               // scratch; overwritten by gather

    const int block = 256;
    const int gridV = min(4096, (E / 4 + block - 1) / block);
    const int gridE = min(4096, (E + block - 1) / block);
    const int gridZ = ((R * N) / 4 + block - 1) / block + 1;

    zero_kernel<<<gridZ, block, 0, stream>>>(counts8, R * N);
    if (R == 8) {
        rank_hist_kernel<8><<<(E & 3) ? gridE : gridV, block, 0, stream>>>(
            edge, dim_p, counts8, rank, E, N);
        scanA_kernel<8><<<NB, block, 0, stream>>>(counts8, offsets, partials, N);
        place_kernel<8><<<(E & 3) ? gridE : gridV, block, 0, stream>>>(
            edge, dim_p, offsets, counts8, rank, partials, perm, E, N, NB);
    } else {
        rank_hist_kernel<1><<<(E & 3) ? gridE : gridV, block, 0, stream>>>(
            edge, dim_p, counts8, rank, E, N);
        scanA_kernel<1><<<NB, block, 0, stream>>>(counts8, offsets, partials, N);
        place_kernel<1><<<(E & 3) ? gridE : gridV, block, 0, stream>>>(
            edge, dim_p, offsets, counts8, rank, partials, perm, E, N, NB);
    }

    const int gridN = (N + 3) / 4;
    gather_kernel<<<gridN, block, 0, stream>>>(
        edge_w, offsets, partials, perm, out, N, E, NB);
}